// Round 1
// baseline (482.744 us; speedup 1.0000x reference)
//
#include <hip/hip_runtime.h>

// Problem constants
#define S_SPANS 4096
#define KANT    64
#define NMENT   4096
#define GDIM    512
#define NPAD    160   // 150 padded to 160 (10 n-tiles of 16)
#define NOUT    150

typedef __bf16 bf16x8 __attribute__((ext_vector_type(8)));
typedef float  f32x4  __attribute__((ext_vector_type(4)));

__device__ __forceinline__ unsigned short f2bf(float x) {
    // round-to-nearest-even float -> bf16 bits (inputs are finite/normal)
    unsigned u = __builtin_bit_cast(unsigned, x);
    u += 0x7fffu + ((u >> 16) & 1u);
    return (unsigned short)(u >> 16);
}

// ---------------------------------------------------------------------------
// P0: transpose W1 blocks to bf16 K-major [160][512] (WaT, WbT, WcT) and
//     build combined phi table PhiW[210][160] = DW[bk]+GW[gen]+SW[spk] (@W1d)
// ---------------------------------------------------------------------------
__global__ void p0_prep(const float* __restrict__ W1,
                        const float* __restrict__ de,
                        const float* __restrict__ ge,
                        const float* __restrict__ se,
                        unsigned short* __restrict__ WT,   // [3][160][512] bf16
                        float* __restrict__ PhiW)          // [210][160] f32
{
    const int NT = 3 * NPAD * GDIM;  // 245760
    int idx = blockIdx.x * 256 + threadIdx.x;
    if (idx < NT) {
        int j = idx / (NPAD * GDIM);
        int r = idx % (NPAD * GDIM);
        int n = r >> 9;          // /512
        int k = r & 511;
        float v = (n < NOUT) ? W1[(j * GDIM + k) * NOUT + n] : 0.0f;
        WT[idx] = f2bf(v);       // linear layout == [j][n][k]
    } else {
        int e = idx - NT;
        if (e < 210 * NPAD) {
            int c = e / NPAD, n = e % NPAD;
            float acc = 0.0f;
            if (n < NOUT) {
                int bk = c / 21, rest = c % 21, g = rest / 3, sp = rest % 3;
                #pragma unroll 4
                for (int d = 0; d < 20; ++d) {
                    acc += de[bk * 20 + d] * W1[(1536 + d) * NOUT + n];
                    acc += ge[g  * 20 + d] * W1[(1556 + d) * NOUT + n];
                    acc += se[sp * 20 + d] * W1[(1576 + d) * NOUT + n];
                }
            }
            PhiW[e] = acc;
        }
    }
}

// ---------------------------------------------------------------------------
// P1: NodeI = g_i @ W1a + b1, NodeJ = g_i @ W1b   (both [4096][160] f32)
//     MFMA 16x16x32 bf16; block = 64 rows, 4 waves x (16 rows x 160 cols)
// ---------------------------------------------------------------------------
__global__ __launch_bounds__(256, 2) void p1_node(
    const float* __restrict__ g_i,
    const float* __restrict__ b1,
    const unsigned short* __restrict__ WT,   // WaT at 0, WbT at +81920 elems
    float* __restrict__ NodeI,
    float* __restrict__ NodeJ)
{
    __shared__ __align__(16) unsigned short Alds[64 * 520]; // row stride 520 (16B-aligned, 2-way bank alias = free)
    const int tid = threadIdx.x;
    const int m0 = blockIdx.x * 64;

    // stage 64 g_i rows as bf16
    const float4* g4 = (const float4*)g_i;
    #pragma unroll 4
    for (int q = tid; q < 64 * 128; q += 256) {
        int pl = q >> 7, f = q & 127;
        float4 v = g4[(m0 + pl) * 128 + f];
        unsigned lo = (unsigned)f2bf(v.x) | ((unsigned)f2bf(v.y) << 16);
        unsigned hi = (unsigned)f2bf(v.z) | ((unsigned)f2bf(v.w) << 16);
        *(uint2*)&Alds[pl * 520 + f * 4] = make_uint2(lo, hi);
    }
    __syncthreads();

    const int lane = tid & 63, w = tid >> 6;
    const int col = lane & 15, quad = lane >> 4;
    const int rowL = w * 16 + col;

    f32x4 accI[10], accJ[10];
    #pragma unroll
    for (int t = 0; t < 10; ++t) { accI[t] = f32x4{0.f,0.f,0.f,0.f}; accJ[t] = f32x4{0.f,0.f,0.f,0.f}; }

    const bf16x8* Av = (const bf16x8*)Alds;
    const bf16x8* Ba = (const bf16x8*)WT;                    // [160][512]
    const bf16x8* Bb = (const bf16x8*)(WT + NPAD * GDIM);    // +81920 elems

    #pragma unroll 2
    for (int ks = 0; ks < 16; ++ks) {
        bf16x8 a = Av[rowL * 65 + ks * 4 + quad];
        #pragma unroll
        for (int t = 0; t < 10; ++t) {
            int n = t * 16 + col;
            bf16x8 ba = Ba[n * 64 + ks * 4 + quad];
            bf16x8 bb = Bb[n * 64 + ks * 4 + quad];
            accI[t] = __builtin_amdgcn_mfma_f32_16x16x32_bf16(a, ba, accI[t], 0, 0, 0);
            accJ[t] = __builtin_amdgcn_mfma_f32_16x16x32_bf16(a, bb, accJ[t], 0, 0, 0);
        }
    }

    // C/D layout: col = lane&15, row = quad*4 + reg
    #pragma unroll
    for (int t = 0; t < 10; ++t) {
        int n = t * 16 + col;
        float b1v = (n < NOUT) ? b1[n] : 0.0f;
        #pragma unroll
        for (int r = 0; r < 4; ++r) {
            int row = m0 + w * 16 + quad * 4 + r;
            NodeI[row * NPAD + n] = accI[t][r] + b1v;
            NodeJ[row * NPAD + n] = accJ[t][r];
        }
    }
}

// ---------------------------------------------------------------------------
// Main: per span row s (64 pairs): C = (i∘j)@Wc via MFMA, z = C + NodeI[m]
//       + NodeJ[a] + PhiW[combo]; s_ij = relu(z)·W2 + b2; fused masked
//       softmax over 64 antecedents + epsilon column; pad invalid with 1000.
// ---------------------------------------------------------------------------
__global__ __launch_bounds__(256, 2) void pair_score_kernel(
    const float* __restrict__ g_i,
    const float* __restrict__ msc,
    const float* __restrict__ W2,
    const float* __restrict__ b2,
    const int* __restrict__ mention_ids,
    const int* __restrict__ ant_ids,
    const int* __restrict__ dists,
    const int* __restrict__ genres,
    const int* __restrict__ speakers,
    const int* __restrict__ ant_counts,
    const unsigned short* __restrict__ WcT,  // [160][512] bf16
    const float* __restrict__ NodeI,
    const float* __restrict__ NodeJ,
    const float* __restrict__ PhiW,
    float* __restrict__ out)
{
    __shared__ __align__(16) unsigned short Alds[64 * 520];
    __shared__ int   m_lds[64], a_lds[64], c_lds[64];
    __shared__ float msum_lds[64], sc_lds[64];
    __shared__ int   cnt_lds;

    const int tid = threadIdx.x;
    const int s = blockIdx.x;

    // phase 1: per-pair metadata
    if (tid < 64) {
        int p = s * 64 + tid;
        int m = mention_ids[p], a = ant_ids[p];
        int d = dists[p];
        int bk = (d>=1)+(d>=2)+(d>=3)+(d>=4)+(d>=8)+(d>=16)+(d>=32)+(d>=64);
        m_lds[tid] = m;
        a_lds[tid] = a;
        c_lds[tid] = (bk * 7 + genres[p]) * 3 + speakers[p];
        msum_lds[tid] = msc[m] + msc[a] + b2[0];
    }
    if (tid == 64) cnt_lds = ant_counts[s];
    __syncthreads();

    // phase 2: stage A = (i_g * j_g) as bf16 into LDS
    const float4* g4 = (const float4*)g_i;
    #pragma unroll 4
    for (int q = tid; q < 64 * 128; q += 256) {
        int pl = q >> 7, f = q & 127;
        int m = m_lds[pl], a = a_lds[pl];
        float4 vi = g4[m * 128 + f];
        float4 vj = g4[a * 128 + f];
        unsigned lo = (unsigned)f2bf(vi.x * vj.x) | ((unsigned)f2bf(vi.y * vj.y) << 16);
        unsigned hi = (unsigned)f2bf(vi.z * vj.z) | ((unsigned)f2bf(vi.w * vj.w) << 16);
        *(uint2*)&Alds[pl * 520 + f * 4] = make_uint2(lo, hi);
    }
    __syncthreads();

    // phase 3: GEMM — wave w owns pairs [w*16, w*16+16), n-tiles 0..9
    const int lane = tid & 63, w = tid >> 6;
    const int col = lane & 15, quad = lane >> 4;
    const int rowL = w * 16 + col;

    f32x4 acc[10];
    #pragma unroll
    for (int t = 0; t < 10; ++t) acc[t] = f32x4{0.f,0.f,0.f,0.f};

    const bf16x8* Av = (const bf16x8*)Alds;
    const bf16x8* Bv = (const bf16x8*)WcT;

    #pragma unroll 4
    for (int ks = 0; ks < 16; ++ks) {
        bf16x8 a = Av[rowL * 65 + ks * 4 + quad];
        bf16x8 b[10];
        #pragma unroll
        for (int t = 0; t < 10; ++t) b[t] = Bv[(t * 16 + col) * 64 + ks * 4 + quad];
        #pragma unroll
        for (int t = 0; t < 10; ++t)
            acc[t] = __builtin_amdgcn_mfma_f32_16x16x32_bf16(a, b[t], acc[t], 0, 0, 0);
    }

    // phase 4: epilogue — z, relu, dot with W2, reduce across 16 cols
    int mrow[4], arow[4], crow[4];
    float msv[4];
    #pragma unroll
    for (int r = 0; r < 4; ++r) {
        int pl = w * 16 + quad * 4 + r;
        mrow[r] = m_lds[pl]; arow[r] = a_lds[pl]; crow[r] = c_lds[pl];
        msv[r] = msum_lds[pl];
    }
    float sums[4] = {0.f, 0.f, 0.f, 0.f};
    #pragma unroll
    for (int t = 0; t < 10; ++t) {
        int n = t * 16 + col;
        float w2v = (n < NOUT) ? W2[n] : 0.0f;
        #pragma unroll
        for (int r = 0; r < 4; ++r) {
            float z = acc[t][r] + NodeI[mrow[r] * NPAD + n]
                                + NodeJ[arow[r] * NPAD + n]
                                + PhiW[crow[r] * NPAD + n];
            sums[r] += fmaxf(z, 0.0f) * w2v;
        }
    }
    #pragma unroll
    for (int r = 0; r < 4; ++r) {
        float v = sums[r];
        v += __shfl_xor(v, 1); v += __shfl_xor(v, 2);
        v += __shfl_xor(v, 4); v += __shfl_xor(v, 8);
        if (col == 0) sc_lds[w * 16 + quad * 4 + r] = v + msv[r];
    }
    __syncthreads();

    // phase 5: masked softmax over K=64 + epsilon column (wave 0)
    if (tid < 64) {
        int cnt = cnt_lds;
        bool valid = tid < cnt;
        float logit = valid ? sc_lds[tid] : -1e30f;
        float mx = logit;
        mx = fmaxf(mx, __shfl_xor(mx, 1));  mx = fmaxf(mx, __shfl_xor(mx, 2));
        mx = fmaxf(mx, __shfl_xor(mx, 4));  mx = fmaxf(mx, __shfl_xor(mx, 8));
        mx = fmaxf(mx, __shfl_xor(mx, 16)); mx = fmaxf(mx, __shfl_xor(mx, 32));
        mx = fmaxf(mx, 0.0f);  // epsilon logit = 0
        float e = __expf(logit - mx);
        float ssum = e;
        ssum += __shfl_xor(ssum, 1);  ssum += __shfl_xor(ssum, 2);
        ssum += __shfl_xor(ssum, 4);  ssum += __shfl_xor(ssum, 8);
        ssum += __shfl_xor(ssum, 16); ssum += __shfl_xor(ssum, 32);
        float eps = __expf(-mx);
        ssum += eps;
        float* orow = out + s * 65;
        orow[tid] = valid ? (e / ssum) : 1000.0f;
        if (tid == 0) orow[64] = eps / ssum;
    }
}

// ---------------------------------------------------------------------------
extern "C" void kernel_launch(void* const* d_in, const int* in_sizes, int n_in,
                              void* d_out, int out_size, void* d_ws, size_t ws_size,
                              hipStream_t stream)
{
    const float* g_i = (const float*)d_in[0];
    const float* msc = (const float*)d_in[1];
    const float* de  = (const float*)d_in[2];
    const float* ge  = (const float*)d_in[3];
    const float* se  = (const float*)d_in[4];
    const float* W1  = (const float*)d_in[5];
    const float* b1  = (const float*)d_in[6];
    const float* W2  = (const float*)d_in[7];
    const float* b2  = (const float*)d_in[8];
    const int* mid  = (const int*)d_in[9];
    const int* aid  = (const int*)d_in[10];
    const int* dst  = (const int*)d_in[11];
    const int* gen  = (const int*)d_in[12];
    const int* spk  = (const int*)d_in[13];
    const int* cnts = (const int*)d_in[14];

    // workspace layout (bytes):
    //   WT   [3][160][512] bf16 : 0        .. 491520
    //   PhiW [210][160] f32     : 491520   .. 625920
    //   NodeI[4096][160] f32    : 625920   .. 3247360
    //   NodeJ[4096][160] f32    : 3247360  .. 5868800
    char* ws = (char*)d_ws;
    unsigned short* WT = (unsigned short*)ws;
    float* PhiW  = (float*)(ws + 491520);
    float* NodeI = (float*)(ws + 625920);
    float* NodeJ = (float*)(ws + 3247360);

    const int p0_elems = 3 * NPAD * GDIM + 210 * NPAD;  // 279360
    p0_prep<<<dim3((p0_elems + 255) / 256), dim3(256), 0, stream>>>(
        W1, de, ge, se, WT, PhiW);

    p1_node<<<dim3(NMENT / 64), dim3(256), 0, stream>>>(
        g_i, b1, WT, NodeI, NodeJ);

    pair_score_kernel<<<dim3(S_SPANS), dim3(256), 0, stream>>>(
        g_i, msc, W2, b2, mid, aid, dst, gen, spk, cnts,
        WT + 2 * NPAD * GDIM, NodeI, NodeJ, PhiW, (float*)d_out);
}

// Round 2
// 431.393 us; speedup vs baseline: 1.1190x; 1.1190x over previous
//
#include <hip/hip_runtime.h>

#define NMENT 4096
#define GDIM  512
#define NPAD  160
#define NOUT  150

typedef _Float16 f16x8 __attribute__((ext_vector_type(8)));
typedef float    f32x4 __attribute__((ext_vector_type(4)));

// workspace layout (bytes)
#define G16_OFF   0u         // [4096][512] f16  = 4194304
#define WT_OFF    4194304u   // [3][160][512] f16 = 491520 (Wa,Wb,Wc K-major)
#define PHI_OFF   4685824u   // [210][160] f16   = 67200
#define NODEI_OFF 4753024u   // [4096][160] f16  = 1310720
#define NODEJ_OFF 6063744u   // [4096][160] f16  = 1310720
#define B1P_OFF   7374464u   // [160] f32
#define W2P_OFF   7375104u   // [160] f32
// total 7375744 bytes (~7.0 MiB)

// ---------------------------------------------------------------------------
// prep: g16 conversion (blocks 0..1023), W1a/b/c transpose to f16 K-major
// (blocks 1024..1047), PhiW table (1048..1179), padded b1/W2 (1180..1181)
// ---------------------------------------------------------------------------
__global__ void prep_kernel(const float* __restrict__ g_i,
                            const float* __restrict__ de,
                            const float* __restrict__ ge,
                            const float* __restrict__ se,
                            const float* __restrict__ W1,
                            const float* __restrict__ b1,
                            const float* __restrict__ W2,
                            _Float16* __restrict__ g16,
                            _Float16* __restrict__ WT,
                            _Float16* __restrict__ PhiW,
                            float* __restrict__ b1p,
                            float* __restrict__ W2p)
{
    __shared__ float tl[64 * 152];
    const int b = blockIdx.x, tid = threadIdx.x;

    if (b < 1024) {
        // g_i -> f16, 2048 floats per block
        const float4* g4 = (const float4*)g_i;
        int i4 = b * 512 + tid * 2;
        float4 v0 = g4[i4], v1 = g4[i4 + 1];
        f16x8 h = {(_Float16)v0.x, (_Float16)v0.y, (_Float16)v0.z, (_Float16)v0.w,
                   (_Float16)v1.x, (_Float16)v1.y, (_Float16)v1.z, (_Float16)v1.w};
        ((uint4*)g16)[b * 256 + tid] = __builtin_bit_cast(uint4, h);
    } else if (b < 1048) {
        // transpose one 64-row strip of W1 section j into WT[j][n][k]
        int b2 = b - 1024, j = b2 >> 3, k0 = (b2 & 7) << 6;
        int rbase = j * 512 + k0;
        for (int idx = tid; idx < 64 * 150; idx += 256) {
            int kk = idx / 150, col = idx - kk * 150;
            tl[kk * 152 + col] = W1[(rbase + kk) * 150 + col];
        }
        __syncthreads();
        for (int idx = tid; idx < 160 * 64; idx += 256) {
            int n = idx >> 6, k = idx & 63;
            float v = (n < 150) ? tl[k * 152 + n] : 0.0f;
            WT[j * 81920 + n * 512 + k0 + k] = (_Float16)v;
        }
    } else if (b < 1180) {
        int e = (b - 1048) * 256 + tid;
        if (e < 210 * 160) {
            int c = e / 160, n = e - c * 160;
            float acc = 0.0f;
            if (n < 150) {
                int bk = c / 21, rest = c - bk * 21, gi = rest / 3, sp = rest - gi * 3;
                #pragma unroll 4
                for (int d = 0; d < 20; ++d) {
                    acc += de[bk * 20 + d] * W1[(1536 + d) * 150 + n];
                    acc += ge[gi * 20 + d] * W1[(1556 + d) * 150 + n];
                    acc += se[sp * 20 + d] * W1[(1576 + d) * 150 + n];
                }
            }
            PhiW[e] = (_Float16)acc;
        }
    } else if (b == 1180) {
        if (tid < 160) b1p[tid] = (tid < 150) ? b1[tid] : 0.0f;
    } else {
        if (tid < 160) W2p[tid] = (tid < 150) ? W2[tid] : 0.0f;
    }
}

// ---------------------------------------------------------------------------
// p1: NodeI = g16 @ WaT + b1 ; NodeJ = g16 @ WbT  (f16 out, [4096][160])
// grid (64, 2): y=0 -> NodeI, y=1 -> NodeJ; block = 64 rows, 4 waves:
// wave w: row-half (w>>1)*32, n-half (w&1)*80. Direct-from-global fragments.
// ---------------------------------------------------------------------------
__global__ void p1_node(const _Float16* __restrict__ g16,
                        const _Float16* __restrict__ WT,
                        const float* __restrict__ b1p,
                        _Float16* __restrict__ NodeI,
                        _Float16* __restrict__ NodeJ)
{
    const int tid = threadIdx.x, y = blockIdx.y;
    const int lane = tid & 63, w = tid >> 6;
    const int col = lane & 15, quad = lane >> 4;
    const int mhalf = w >> 1, nhalf = w & 1;
    const int rowbase = blockIdx.x * 64 + mhalf * 32;

    const uint4* G = (const uint4*)g16;                  // row stride 64 uint4
    const uint4* B = (const uint4*)(WT + y * 81920);
    _Float16* out = y ? NodeJ : NodeI;

    const uint4* a0p = G + (rowbase + col) * 64 + quad;
    const uint4* a1p = G + (rowbase + 16 + col) * 64 + quad;
    const uint4* bp[5];
    #pragma unroll
    for (int t = 0; t < 5; ++t)
        bp[t] = B + (nhalf * 80 + t * 16 + col) * 64 + quad;

    f32x4 acc[2][5];
    #pragma unroll
    for (int mt = 0; mt < 2; ++mt)
        #pragma unroll
        for (int t = 0; t < 5; ++t) acc[mt][t] = f32x4{0.f, 0.f, 0.f, 0.f};

    #pragma unroll 2
    for (int s = 0; s < 16; ++s) {
        f16x8 a0 = __builtin_bit_cast(f16x8, a0p[s * 4]);
        f16x8 a1 = __builtin_bit_cast(f16x8, a1p[s * 4]);
        #pragma unroll
        for (int t = 0; t < 5; ++t) {
            f16x8 bf = __builtin_bit_cast(f16x8, bp[t][s * 4]);
            acc[0][t] = __builtin_amdgcn_mfma_f32_16x16x32_f16(a0, bf, acc[0][t], 0, 0, 0);
            acc[1][t] = __builtin_amdgcn_mfma_f32_16x16x32_f16(a1, bf, acc[1][t], 0, 0, 0);
        }
    }

    #pragma unroll
    for (int mt = 0; mt < 2; ++mt)
        #pragma unroll
        for (int t = 0; t < 5; ++t) {
            int n = nhalf * 80 + t * 16 + col;
            float bias = y ? 0.0f : b1p[n];
            #pragma unroll
            for (int r = 0; r < 4; ++r) {
                int row = rowbase + mt * 16 + quad * 4 + r;
                out[row * NPAD + n] = (_Float16)(acc[mt][t][r] + bias);
            }
        }
}

// ---------------------------------------------------------------------------
// main: block = 1 span row (64 pairs), 4 waves: wave (ph, nh) = 32 pairs x
// 80 n-cols. A-fragments (i*j product) built in registers from g16 gather;
// B direct from WcT (L1/L2-resident). Epilogue: +NodeI/NodeJ/PhiW (f16
// gathers), relu, dot W2; partial sums -> LDS; fused masked softmax + pad.
// ---------------------------------------------------------------------------
__global__ void pair_score_kernel(
    const _Float16* __restrict__ g16,
    const _Float16* __restrict__ WcT,
    const _Float16* __restrict__ NodeI,
    const _Float16* __restrict__ NodeJ,
    const _Float16* __restrict__ PhiW,
    const float* __restrict__ W2p,
    const float* __restrict__ msc,
    const float* __restrict__ b2,
    const int* __restrict__ mention_ids,
    const int* __restrict__ ant_ids,
    const int* __restrict__ dists,
    const int* __restrict__ genres,
    const int* __restrict__ speakers,
    const int* __restrict__ ant_counts,
    float* __restrict__ out)
{
    __shared__ float sc[2][64];

    const int tid = threadIdx.x, s = blockIdx.x;
    const int lane = tid & 63, w = tid >> 6;
    const int col = lane & 15, quad = lane >> 4;
    const int ph = w >> 1, nh = w & 1;

    // per-lane pair metadata for the wave's two 16-pair m-tiles
    const int p0 = s * 64 + ph * 32 + col;
    const int p1 = p0 + 16;
    const int m0 = mention_ids[p0], a0 = ant_ids[p0];
    const int m1 = mention_ids[p1], a1 = ant_ids[p1];

    int d0 = dists[p0], d1 = dists[p1];
    int bk0 = (d0>=1)+(d0>=2)+(d0>=3)+(d0>=4)+(d0>=8)+(d0>=16)+(d0>=32)+(d0>=64);
    int bk1 = (d1>=1)+(d1>=2)+(d1>=3)+(d1>=4)+(d1>=8)+(d1>=16)+(d1>=32)+(d1>=64);
    const int c0 = (bk0 * 7 + genres[p0]) * 3 + speakers[p0];
    const int c1 = (bk1 * 7 + genres[p1]) * 3 + speakers[p1];
    const float ms0 = msc[m0] + msc[a0];
    const float ms1 = msc[m1] + msc[a1];

    // K-loop: A from g16 (i*j packed-f16 product), B from WcT
    const uint4* G = (const uint4*)g16;
    const uint4* B = (const uint4*)WcT;
    const uint4* gi0 = G + m0 * 64 + quad;
    const uint4* gj0 = G + a0 * 64 + quad;
    const uint4* gi1 = G + m1 * 64 + quad;
    const uint4* gj1 = G + a1 * 64 + quad;
    const uint4* bp[5];
    #pragma unroll
    for (int t = 0; t < 5; ++t)
        bp[t] = B + (nh * 80 + t * 16 + col) * 64 + quad;

    f32x4 acc[2][5];
    #pragma unroll
    for (int mt = 0; mt < 2; ++mt)
        #pragma unroll
        for (int t = 0; t < 5; ++t) acc[mt][t] = f32x4{0.f, 0.f, 0.f, 0.f};

    #pragma unroll 2
    for (int ks = 0; ks < 16; ++ks) {
        f16x8 i0 = __builtin_bit_cast(f16x8, gi0[ks * 4]);
        f16x8 j0 = __builtin_bit_cast(f16x8, gj0[ks * 4]);
        f16x8 i1 = __builtin_bit_cast(f16x8, gi1[ks * 4]);
        f16x8 j1 = __builtin_bit_cast(f16x8, gj1[ks * 4]);
        f16x8 af0 = i0 * j0;            // v_pk_mul_f16 x4
        f16x8 af1 = i1 * j1;
        #pragma unroll
        for (int t = 0; t < 5; ++t) {
            f16x8 bf = __builtin_bit_cast(f16x8, bp[t][ks * 4]);
            acc[0][t] = __builtin_amdgcn_mfma_f32_16x16x32_f16(af0, bf, acc[0][t], 0, 0, 0);
            acc[1][t] = __builtin_amdgcn_mfma_f32_16x16x32_f16(af1, bf, acc[1][t], 0, 0, 0);
        }
    }

    // epilogue: gather Node/Phi rows for the 8 output rows this lane reduces
    int mr[2][4], ar[2][4], cr[2][4];
    #pragma unroll
    for (int r = 0; r < 4; ++r) {
        int src = quad * 4 + r;
        mr[0][r] = __shfl(m0, src); ar[0][r] = __shfl(a0, src); cr[0][r] = __shfl(c0, src);
        mr[1][r] = __shfl(m1, src); ar[1][r] = __shfl(a1, src); cr[1][r] = __shfl(c1, src);
    }

    float sums[2][4] = {{0.f,0.f,0.f,0.f},{0.f,0.f,0.f,0.f}};
    #pragma unroll
    for (int t = 0; t < 5; ++t) {
        int n = nh * 80 + t * 16 + col;
        float w2v = W2p[n];
        #pragma unroll
        for (int mt = 0; mt < 2; ++mt)
            #pragma unroll
            for (int r = 0; r < 4; ++r) {
                float z = acc[mt][t][r]
                        + (float)NodeI[mr[mt][r] * NPAD + n]
                        + (float)NodeJ[ar[mt][r] * NPAD + n]
                        + (float)PhiW[cr[mt][r] * NPAD + n];
                sums[mt][r] += fmaxf(z, 0.0f) * w2v;
            }
    }

    const float b2v = b2[0];
    #pragma unroll
    for (int mt = 0; mt < 2; ++mt)
        #pragma unroll
        for (int r = 0; r < 4; ++r) {
            float v = sums[mt][r];
            v += __shfl_xor(v, 1); v += __shfl_xor(v, 2);
            v += __shfl_xor(v, 4); v += __shfl_xor(v, 8);
            if (col == 0) {
                float extra = 0.0f;
                if (nh == 0) {
                    float ms = __shfl(mt ? ms1 : ms0, quad * 4 + r);
                    extra = ms + b2v;
                }
                sc[nh][ph * 32 + mt * 16 + quad * 4 + r] = v + extra;
            }
        }
    __syncthreads();

    // fused masked softmax over 64 antecedents + epsilon column
    if (tid < 64) {
        int cnt = ant_counts[s];
        bool valid = tid < cnt;
        float logit = valid ? (sc[0][tid] + sc[1][tid]) : -1e30f;
        float mx = logit;
        mx = fmaxf(mx, __shfl_xor(mx, 1));  mx = fmaxf(mx, __shfl_xor(mx, 2));
        mx = fmaxf(mx, __shfl_xor(mx, 4));  mx = fmaxf(mx, __shfl_xor(mx, 8));
        mx = fmaxf(mx, __shfl_xor(mx, 16)); mx = fmaxf(mx, __shfl_xor(mx, 32));
        mx = fmaxf(mx, 0.0f);  // epsilon logit = 0
        float e = __expf(logit - mx);
        float ssum = e;
        ssum += __shfl_xor(ssum, 1);  ssum += __shfl_xor(ssum, 2);
        ssum += __shfl_xor(ssum, 4);  ssum += __shfl_xor(ssum, 8);
        ssum += __shfl_xor(ssum, 16); ssum += __shfl_xor(ssum, 32);
        float eps = __expf(-mx);
        ssum += eps;
        float* orow = out + s * 65;
        orow[tid] = valid ? (e / ssum) : 1000.0f;
        if (tid == 0) orow[64] = eps / ssum;
    }
}

// ---------------------------------------------------------------------------
extern "C" void kernel_launch(void* const* d_in, const int* in_sizes, int n_in,
                              void* d_out, int out_size, void* d_ws, size_t ws_size,
                              hipStream_t stream)
{
    const float* g_i = (const float*)d_in[0];
    const float* msc = (const float*)d_in[1];
    const float* de  = (const float*)d_in[2];
    const float* ge  = (const float*)d_in[3];
    const float* se  = (const float*)d_in[4];
    const float* W1  = (const float*)d_in[5];
    const float* b1  = (const float*)d_in[6];
    const float* W2  = (const float*)d_in[7];
    const float* b2  = (const float*)d_in[8];
    const int* mid  = (const int*)d_in[9];
    const int* aid  = (const int*)d_in[10];
    const int* dst  = (const int*)d_in[11];
    const int* gen  = (const int*)d_in[12];
    const int* spk  = (const int*)d_in[13];
    const int* cnts = (const int*)d_in[14];

    char* ws = (char*)d_ws;
    _Float16* g16   = (_Float16*)(ws + G16_OFF);
    _Float16* WT    = (_Float16*)(ws + WT_OFF);
    _Float16* PhiW  = (_Float16*)(ws + PHI_OFF);
    _Float16* NodeI = (_Float16*)(ws + NODEI_OFF);
    _Float16* NodeJ = (_Float16*)(ws + NODEJ_OFF);
    float*    b1p   = (float*)(ws + B1P_OFF);
    float*    W2p   = (float*)(ws + W2P_OFF);

    prep_kernel<<<dim3(1182), dim3(256), 0, stream>>>(
        g_i, de, ge, se, W1, b1, W2, g16, WT, PhiW, b1p, W2p);

    p1_node<<<dim3(64, 2), dim3(256), 0, stream>>>(
        g16, WT, b1p, NodeI, NodeJ);

    pair_score_kernel<<<dim3(4096), dim3(256), 0, stream>>>(
        g16, WT + 2 * 81920, NodeI, NodeJ, PhiW, W2p, msc, b2,
        mid, aid, dst, gen, spk, cnts, (float*)d_out);
}